// Round 1
// baseline (245.822 us; speedup 1.0000x reference)
//
#include <hip/hip_runtime.h>

// SeaThru-NeRF RGB renderer forward pass, round 4.
//
// RESTRUCTURE vs R3: one BLOCK (256 threads) per ray, ONE sample per thread
// (was: one wave per ray, 4 samples/lane). R3's counters showed VGPR=40
// (launch_bounds(256,2) had no effect) with ~100 live floats in source ->
// the backend sank/scalarized the bulk loads and the wave ran latency-bound
// (VALUBusy 14%, HBM 25% of peak, occupancy 56%, nothing saturated).
// With 1 sample/thread the per-thread footprint is ~55 regs by construction:
// no spills, no load sinking, 4x the waves for TLP.
//
// Math: all 7 exclusive cumsum scans (density + 3 direct + 3 backscatter)
// are done as ONE 7-wide interleaved wave scan + LDS cross-wave prefix.
// T*direct_attenuation and T*backscattering are fused into single scans
// (exp(-scan(a))*exp(-scan(b)) == exp(-scan(a+b))), and log2(e) is folded
// into deltas once so every exponential is a bare exp2f (v_exp_f32).

#define LOG2E 1.4426950408889634f

struct F3 { float x, y, z; };   // 12B packed, 4B aligned -> global_load_dwordx3

__device__ __forceinline__ float clip01(float x) {
    return fminf(fmaxf(x, 0.0f), 1.0f);
}

__global__ __launch_bounds__(256, 4) void seathru_render(
    const float* __restrict__ g_orgb,   // [R,S,3] object_rgbs
    const float* __restrict__ g_mrgb,   // [R,S,3] medium_rgbs
    const float* __restrict__ g_dc,     // [R,S,3] direct_coeffs
    const float* __restrict__ g_bc,     // [R,S,3] backscatter_coeffs
    const float* __restrict__ g_den,    // [R,S,1] densities
    const float* __restrict__ g_del,    // [R,S,1] deltas
    float* __restrict__ out, int R)
{
    const int S = 256;
    const int ray  = blockIdx.x;        // one block per ray
    const int tid  = threadIdx.x;       // sample index 0..255
    const int lane = tid & 63;
    const int wv   = tid >> 6;          // wave 0..3

    const size_t b1 = (size_t)ray * S + tid;
    const size_t b3 = b1 * 3;
    const size_t RS = (size_t)R * S;

    // ---- loads: 12B/thread per RGB array + 2 scalars, all coalesced ----
    const float del = g_del[b1] * LOG2E;     // log2e folded in once
    const float den = g_den[b1];
    const F3 dc  = *((const F3*)(g_dc   + b3));
    const F3 bc  = *((const F3*)(g_bc   + b3));
    const F3 orv = *((const F3*)(g_orgb + b3));
    const F3 mr  = *((const F3*)(g_mrgb + b3));

    // ---- 7 scan inputs (log2 domain) ----
    const float dd   = del * den;            // density * delta
    const float bsd0 = bc.x * del, bsd1 = bc.y * del, bsd2 = bc.z * del;
    float own[7];
    own[0] = dd;                    // -> object transmittance T
    own[1] = dd + dc.x * del;       // -> T * direct_attenuation (fused)
    own[2] = dd + dc.y * del;
    own[3] = dd + dc.z * del;
    own[4] = dd + bsd0;             // -> T * backscattering (fused)
    own[5] = dd + bsd1;
    own[6] = dd + bsd2;

    // ---- 7-wide interleaved inclusive wave scan (6 rounds, ILP across 7) ----
    float v[7];
#pragma unroll
    for (int j = 0; j < 7; ++j) v[j] = own[j];
#pragma unroll
    for (int off = 1; off < 64; off <<= 1) {
        float y[7];
#pragma unroll
        for (int j = 0; j < 7; ++j) y[j] = __shfl_up(v[j], off, 64);
#pragma unroll
        for (int j = 0; j < 7; ++j) v[j] += (lane >= off) ? y[j] : 0.0f;
    }

    // ---- cross-wave exclusive prefix via LDS (wave totals) ----
    __shared__ float s_tot[4][8];
    __shared__ float s_red[4][10];
    if (lane == 63) {
#pragma unroll
        for (int j = 0; j < 7; ++j) s_tot[wv][j] = v[j];
    }
    __syncthreads();

    float ex[7];
#pragma unroll
    for (int j = 0; j < 7; ++j) ex[j] = v[j] - own[j];   // wave-exclusive
#pragma unroll
    for (int w2 = 0; w2 < 3; ++w2) {
        if (wv > w2) {                                   // wave-uniform branch
#pragma unroll
            for (int j = 0; j < 7; ++j) ex[j] += s_tot[w2][j];
        }
    }

    // ---- per-sample outputs ----
    const float T     = exp2f(-ex[0]);
    const float alpha = 1.0f - exp2f(-dd);
    const float w     = T * alpha;

    float* outT = out + (size_t)12 * R;      // object_transmittance [R,S]
    float* outA = outT + RS;                 // object_alphas
    float* outW = outA + RS;                 // object_weights
    outT[b1] = T;
    outA[b1] = alpha;
    outW[b1] = w;

    // ---- per-sample contributions to the 10 per-ray sums ----
    float a[10];
    a[0] = exp2f(-ex[1]) * alpha * orv.x;                    // direct r
    a[1] = exp2f(-ex[2]) * alpha * orv.y;                    // direct g
    a[2] = exp2f(-ex[3]) * alpha * orv.z;                    // direct b
    a[3] = exp2f(-ex[4]) * (1.0f - exp2f(-bsd0)) * mr.x;     // backscatter r
    a[4] = exp2f(-ex[5]) * (1.0f - exp2f(-bsd1)) * mr.y;     // backscatter g
    a[5] = exp2f(-ex[6]) * (1.0f - exp2f(-bsd2)) * mr.z;     // backscatter b
    a[6] = w * orv.x;                                        // restored r
    a[7] = w * orv.y;                                        // restored g
    a[8] = w * orv.z;                                        // restored b
    a[9] = w;                                                // object mask

    // ---- 10-wide interleaved wave reduction ----
#pragma unroll
    for (int off = 32; off; off >>= 1) {
#pragma unroll
        for (int j = 0; j < 10; ++j) a[j] += __shfl_xor(a[j], off, 64);
    }
    if (lane == 0) {
#pragma unroll
        for (int j = 0; j < 10; ++j) s_red[wv][j] = a[j];
    }
    __syncthreads();

    // ---- per-ray outputs (thread 0 also owns sample 0 -> dc0/bc0 raw) ----
    if (tid == 0) {
        float t[10];
#pragma unroll
        for (int j = 0; j < 10; ++j)
            t[j] = s_red[0][j] + s_red[1][j] + s_red[2][j] + s_red[3][j];

        float* rgb  = out;                                  // [R,3]
        float* rest = out + (size_t)3 * R;                  // [R,3]
        float* dir  = out + (size_t)6 * R;                  // [R,3]
        float* bs   = out + (size_t)9 * R;                  // [R,3]
        float* dc0  = out + (size_t)12 * R + 3 * RS;        // direct_coeffs[:,0,:]
        float* bc0  = dc0 + (size_t)3 * R;                  // backscatter_coeffs[:,0,:]
        float* mask = bc0 + (size_t)3 * R;                  // [R,1]

        rgb[ray * 3 + 0]  = clip01(t[0] + t[3]);
        rgb[ray * 3 + 1]  = clip01(t[1] + t[4]);
        rgb[ray * 3 + 2]  = clip01(t[2] + t[5]);
        dir[ray * 3 + 0]  = clip01(t[0]);
        dir[ray * 3 + 1]  = clip01(t[1]);
        dir[ray * 3 + 2]  = clip01(t[2]);
        bs[ray * 3 + 0]   = clip01(t[3]);
        bs[ray * 3 + 1]   = clip01(t[4]);
        bs[ray * 3 + 2]   = clip01(t[5]);
        rest[ray * 3 + 0] = clip01(t[6]);
        rest[ray * 3 + 1] = clip01(t[7]);
        rest[ray * 3 + 2] = clip01(t[8]);
        dc0[ray * 3 + 0]  = dc.x;   // raw sample-0 coeffs
        dc0[ray * 3 + 1]  = dc.y;
        dc0[ray * 3 + 2]  = dc.z;
        bc0[ray * 3 + 0]  = bc.x;
        bc0[ray * 3 + 1]  = bc.y;
        bc0[ray * 3 + 2]  = bc.z;
        mask[ray]         = clip01(t[9]);
    }
}

extern "C" void kernel_launch(void* const* d_in, const int* in_sizes, int n_in,
                              void* d_out, int out_size, void* d_ws, size_t ws_size,
                              hipStream_t stream) {
    const float* orgb = (const float*)d_in[0];
    const float* mrgb = (const float*)d_in[1];
    const float* dc   = (const float*)d_in[2];
    const float* bc   = (const float*)d_in[3];
    const float* den  = (const float*)d_in[4];
    const float* del  = (const float*)d_in[5];

    const int S = 256;
    const int R = in_sizes[0] / (S * 3);

    dim3 block(256);                 // one block = one ray, 1 sample/thread
    dim3 grid(R);
    seathru_render<<<grid, block, 0, stream>>>(orgb, mrgb, dc, bc, den, del,
                                               (float*)d_out, R);
}

// Round 2
// 239.593 us; speedup vs baseline: 1.0260x; 1.0260x over previous
//
#include <hip/hip_runtime.h>

// SeaThru-NeRF RGB renderer forward pass, round 5.
//
// KEY INSIGHT from R4 counters: warm-L3 replay dispatch (52 MB HBM) ran the
// SAME 97us as the cold pass (172 MB) -> duration independent of memory.
// VALUBusy 33%, nothing saturated. Bottleneck: the per-CU LDS/DS pipe.
// Every __shfl_* is a ds_bpermute/ds_permute (~5.8cyc on the shared DS pipe);
// R4 issued ~102/wave x 256 waves/CU ~= 63us of DS-pipe serialization.
//
// FIX: wave64 prefix sums via DPP (row_shr:1/2/4/8 + row_bcast15 + row_bcast31)
// -- pure VALU, zero DS ops, zero waitcnt, zero barriers, zero LDS.
// One wave per ray (4 samples/lane) quarters the per-ray cross-lane count vs
// R4. All loads consumed immediately (alpha*orv, medium_alpha*mrv folded
// pre-scan) so nothing re-loadable is live across the scan -> no sinking.
// Lane 63 (inclusive-scan tail holds all 10 ray totals) writes per-ray
// outputs; lane 0 writes the raw sample-0 coeffs.

#define LOG2E 1.4426950408889634f

__device__ __forceinline__ float clip01(float x) {
    return fminf(fmaxf(x, 0.0f), 1.0f);
}

// DPP move (old=0, bank_mask=0xf). Template params keep builtin args ICE.
template <int CTRL, int ROW_MASK, bool BND>
__device__ __forceinline__ float dpp_mov(float v) {
    return __int_as_float(__builtin_amdgcn_update_dpp(
        0, __float_as_int(v), CTRL, ROW_MASK, 0xf, BND));
}

// N-wide interleaved wave64 INCLUSIVE add-scan, entirely on the VALU pipe.
// row_shr:k = 0x110|k ; row_bcast15 = 0x142 (rows 1,3) ; row_bcast31 = 0x143
// (rows 2,3). Interleaving N independent chains hides the DPP latency.
template <int N>
__device__ __forceinline__ void wave_iscan(float (&v)[N]) {
#pragma unroll
    for (int j = 0; j < N; ++j) v[j] += dpp_mov<0x111, 0xf, true>(v[j]);
#pragma unroll
    for (int j = 0; j < N; ++j) v[j] += dpp_mov<0x112, 0xf, true>(v[j]);
#pragma unroll
    for (int j = 0; j < N; ++j) v[j] += dpp_mov<0x114, 0xf, true>(v[j]);
#pragma unroll
    for (int j = 0; j < N; ++j) v[j] += dpp_mov<0x118, 0xf, true>(v[j]);
#pragma unroll
    for (int j = 0; j < N; ++j) v[j] += dpp_mov<0x142, 0xa, false>(v[j]);
#pragma unroll
    for (int j = 0; j < N; ++j) v[j] += dpp_mov<0x143, 0xc, false>(v[j]);
}

__global__ __launch_bounds__(256, 4) void seathru_render(
    const float* __restrict__ g_orgb,   // [R,S,3] object_rgbs
    const float* __restrict__ g_mrgb,   // [R,S,3] medium_rgbs
    const float* __restrict__ g_dc,     // [R,S,3] direct_coeffs
    const float* __restrict__ g_bc,     // [R,S,3] backscatter_coeffs
    const float* __restrict__ g_den,    // [R,S,1] densities
    const float* __restrict__ g_del,    // [R,S,1] deltas
    float* __restrict__ out, int R)
{
    const int S = 256;
    const int ray  = blockIdx.x * 4 + (threadIdx.x >> 6);  // wave-uniform
    const int lane = threadIdx.x & 63;
    if (ray >= R) return;

    const size_t b3 = (size_t)ray * (S * 3);
    const size_t b1 = (size_t)ray * S;
    const size_t RS = (size_t)R * S;

    // ---- loads: lane owns samples 4*lane .. 4*lane+3 ----
    float4 dl4 = *((const float4*)(g_del + b1) + lane);
    float4 dn4 = *((const float4*)(g_den + b1) + lane);

    float dcv[12], bcv[12], orv[12], mrv[12];
    {
        const float4* p = (const float4*)(g_dc + b3) + lane * 3;
        *(float4*)&dcv[0] = p[0]; *(float4*)&dcv[4] = p[1]; *(float4*)&dcv[8] = p[2];
    }
    {
        const float4* p = (const float4*)(g_bc + b3) + lane * 3;
        *(float4*)&bcv[0] = p[0]; *(float4*)&bcv[4] = p[1]; *(float4*)&bcv[8] = p[2];
    }
    {
        const float4* p = (const float4*)(g_orgb + b3) + lane * 3;
        *(float4*)&orv[0] = p[0]; *(float4*)&orv[4] = p[1]; *(float4*)&orv[8] = p[2];
    }
    {
        const float4* p = (const float4*)(g_mrgb + b3) + lane * 3;
        *(float4*)&mrv[0] = p[0]; *(float4*)&mrv[4] = p[1]; *(float4*)&mrv[8] = p[2];
    }

    const float del[4] = {dl4.x * LOG2E, dl4.y * LOG2E, dl4.z * LOG2E, dl4.w * LOG2E};
    const float den[4] = {dn4.x, dn4.y, dn4.z, dn4.w};

    // ---- thread-local pre-pass: consume orv/mrv NOW (nothing re-loadable
    //      stays live across the scan) ----
    float dd[4], alpha[4];
#pragma unroll
    for (int i = 0; i < 4; ++i) {
        dd[i]    = del[i] * den[i];
        alpha[i] = 1.0f - exp2f(-dd[i]);
    }

    float aorv[12];   // alpha * object_rgb   (feeds direct & restored sums)
    float mamr[12];   // medium_alpha * medium_rgb (feeds backscatter sum)
#pragma unroll
    for (int i = 0; i < 4; ++i) {
#pragma unroll
        for (int c = 0; c < 3; ++c) {
            aorv[i * 3 + c] = alpha[i] * orv[i * 3 + c];
            const float bsd = bcv[i * 3 + c] * del[i];
            mamr[i * 3 + c] = (1.0f - exp2f(-bsd)) * mrv[i * 3 + c];
        }
    }

    // ---- serial (intra-thread) exclusive prefixes for the 7 fused scans:
    //  q0 = dd            -> object transmittance T
    //  q1..3 = dd+dc*del  -> T * direct_attenuation (fused, log2 domain)
    //  q4..6 = dd+bc*del  -> T * backscattering     (fused, log2 domain)
    float ser[7][4];
    float run[7];
#pragma unroll
    for (int q = 0; q < 7; ++q) run[q] = 0.0f;
#pragma unroll
    for (int i = 0; i < 4; ++i) {
        ser[0][i] = run[0]; run[0] += dd[i];
#pragma unroll
        for (int c = 0; c < 3; ++c) {
            ser[1 + c][i] = run[1 + c]; run[1 + c] += dd[i] + dcv[i * 3 + c] * del[i];
            ser[4 + c][i] = run[4 + c]; run[4 + c] += dd[i] + bcv[i * 3 + c] * del[i];
        }
    }

    // ---- 7-wide interleaved DPP wave scan of the thread totals ----
    float sc[7];
#pragma unroll
    for (int q = 0; q < 7; ++q) sc[q] = run[q];
    wave_iscan<7>(sc);
    float off[7];
#pragma unroll
    for (int q = 0; q < 7; ++q) off[q] = sc[q] - run[q];   // wave-exclusive

    // ---- per-sample outputs ----
    float T[4], w[4];
#pragma unroll
    for (int i = 0; i < 4; ++i) {
        T[i] = exp2f(-(off[0] + ser[0][i]));
        w[i] = T[i] * alpha[i];
    }

    float* outT = out + (size_t)12 * R;      // object_transmittance [R,S]
    float* outA = outT + RS;                 // object_alphas
    float* outW = outA + RS;                 // object_weights
    {
        float4 t4 = {T[0], T[1], T[2], T[3]};
        float4 a4 = {alpha[0], alpha[1], alpha[2], alpha[3]};
        float4 w4 = {w[0], w[1], w[2], w[3]};
        *((float4*)(outT + b1) + lane) = t4;
        *((float4*)(outA + b1) + lane) = a4;
        *((float4*)(outW + b1) + lane) = w4;
    }

    // ---- per-thread contributions to the 10 per-ray sums ----
    float acc[10];
#pragma unroll
    for (int c = 0; c < 3; ++c) {
        float ad = 0.0f, ab = 0.0f, ar = 0.0f;
#pragma unroll
        for (int i = 0; i < 4; ++i) {
            ad += exp2f(-(off[1 + c] + ser[1 + c][i])) * aorv[i * 3 + c];
            ab += exp2f(-(off[4 + c] + ser[4 + c][i])) * mamr[i * 3 + c];
            ar += T[i] * aorv[i * 3 + c];
        }
        acc[c]     = ad;   // direct
        acc[3 + c] = ab;   // backscatter
        acc[6 + c] = ar;   // restored
    }
    acc[9] = w[0] + w[1] + w[2] + w[3];      // object mask

    // ---- 10-wide interleaved DPP reduction (inclusive scan; lane 63 = total)
    wave_iscan<10>(acc);

    if (lane == 63) {
        float* rgb  = out;                                  // [R,3]
        float* rest = out + (size_t)3 * R;                  // [R,3]
        float* dir  = out + (size_t)6 * R;                  // [R,3]
        float* bs   = out + (size_t)9 * R;                  // [R,3]
        float* dc0  = out + (size_t)12 * R + 3 * RS;
        float* bc0  = dc0 + (size_t)3 * R;
        float* mask = bc0 + (size_t)3 * R;                  // [R,1]
#pragma unroll
        for (int c = 0; c < 3; ++c) {
            const float d = acc[c], b = acc[3 + c];
            rgb[ray * 3 + c]  = clip01(d + b);
            dir[ray * 3 + c]  = clip01(d);
            bs[ray * 3 + c]   = clip01(b);
            rest[ray * 3 + c] = clip01(acc[6 + c]);
        }
        mask[ray] = clip01(acc[9]);
    }
    if (lane == 0) {
        float* dc0 = out + (size_t)12 * R + 3 * RS;
        float* bc0 = dc0 + (size_t)3 * R;
#pragma unroll
        for (int c = 0; c < 3; ++c) {
            dc0[ray * 3 + c] = dcv[c];   // raw sample-0 coeffs (unscaled)
            bc0[ray * 3 + c] = bcv[c];
        }
    }
}

extern "C" void kernel_launch(void* const* d_in, const int* in_sizes, int n_in,
                              void* d_out, int out_size, void* d_ws, size_t ws_size,
                              hipStream_t stream) {
    const float* orgb = (const float*)d_in[0];
    const float* mrgb = (const float*)d_in[1];
    const float* dc   = (const float*)d_in[2];
    const float* bc   = (const float*)d_in[3];
    const float* den  = (const float*)d_in[4];
    const float* del  = (const float*)d_in[5];

    const int S = 256;
    const int R = in_sizes[0] / (S * 3);

    dim3 block(256);                 // 4 waves = 4 independent rays per block
    dim3 grid((R + 3) / 4);
    seathru_render<<<grid, block, 0, stream>>>(orgb, mrgb, dc, bc, den, del,
                                               (float*)d_out, R);
}